// Round 7
// baseline (175.423 us; speedup 1.0000x reference)
//
#include <hip/hip_runtime.h>

#define EMBED 128
#define NRBF 8
#define CAP 160   // per-atom edge capacity; mean 64, sigma 8 (binomial) -> 12 sigma

typedef __attribute__((ext_vector_type(8))) short bf16x8;
typedef __attribute__((ext_vector_type(4))) float f32x4;

static __device__ __forceinline__ unsigned short f2bf(float f) {
  unsigned u = __builtin_bit_cast(unsigned, f);
  u = (u + 0x7fffu + ((u >> 16) & 1u)) >> 16;  // round-to-nearest-even
  return (unsigned short)u;
}

static __device__ __forceinline__ float silu_f(float x) {
  return x / (1.0f + __expf(-x));
}

// ---------------------------------------------------------------------------
// K0: prep — zero cursor, convert 4 weights to bf16, pack biases.
// ---------------------------------------------------------------------------
__global__ __launch_bounds__(256) void prep_kernel(
    const float* __restrict__ W1, const float* __restrict__ W2,
    const float* __restrict__ W3, const float* __restrict__ Wf,
    const float* __restrict__ b1, const float* __restrict__ b2,
    const float* __restrict__ b3,
    unsigned short* __restrict__ Wbf, float* __restrict__ bws,
    unsigned* __restrict__ cursor, int num_atoms)
{
  int i = blockIdx.x * 256 + threadIdx.x;
  if (i < 16384) {
    Wbf[i]         = f2bf(W1[i]);
    Wbf[16384 + i] = f2bf(W2[i]);
    Wbf[32768 + i] = f2bf(W3[i]);
    Wbf[49152 + i] = f2bf(Wf[i]);
  }
  if (i < 128) {
    bws[i] = b1[i]; bws[128 + i] = b2[i]; bws[256 + i] = b3[i];
  }
  if (i < num_atoms) cursor[i] = 0u;
}

// ---------------------------------------------------------------------------
// K1 (new path, phase A): stream edges in NATURAL ORDER — contiguous 1KB
// m_ji loads (2 edges/wave, f32x4/lane). Compute prod=(rbf.WT)*m, round to
// bf16, scatter-write the 256B row to payload[dst*CAP + pos]. Writes are
// fire-and-forget (no read latency on the random side); bucket_kernel's
// atomic is fused here (pos claim). Replaces the random-512B-read gather.
// ---------------------------------------------------------------------------
__global__ __launch_bounds__(256) void edge_stream_kernel(
    const float* __restrict__ m_ji, const float* __restrict__ e_rbf,
    const int* __restrict__ nbr, const float* __restrict__ W_edge,
    unsigned* __restrict__ cursor, unsigned short* __restrict__ payload,
    int n_edges)
{
  const int lane = threadIdx.x & 63;
  const int li = lane & 31;
  const int half = lane >> 5;
  const int wid = blockIdx.x * (blockDim.x >> 6) + (threadIdx.x >> 6);
  const int n_waves = gridDim.x * (blockDim.x >> 6);

  // transposed edge weights for this lane's 4 channels (c = li*4+q)
  f32x4 wT[NRBF];
#pragma unroll
  for (int k = 0; k < NRBF; ++k) {
#pragma unroll
    for (int q = 0; q < 4; ++q) wT[k][q] = W_edge[(li * 4 + q) * NRBF + k];
  }

  for (int e0 = wid * 2; e0 < n_edges; e0 += n_waves * 2) {
    const int e = e0 + half;                 // this half-wave's edge
    const bool act = (e < n_edges);
    // contiguous 1KB per wave: f32x4 index e0*32 + lane spans rows e0,e0+1
    f32x4 m4 = {0.f, 0.f, 0.f, 0.f};
    if (act) m4 = reinterpret_cast<const f32x4*>(m_ji)[(size_t)e0 * 32 + lane];
    f32x4 r0 = {0.f, 0.f, 0.f, 0.f}, r1 = r0;
    int dst = 0;
    if (act) {
      r0 = reinterpret_cast<const f32x4*>(e_rbf)[(size_t)e * 2];
      r1 = reinterpret_cast<const f32x4*>(e_rbf)[(size_t)e * 2 + 1];
      dst = nbr[2 * e];
    }
    int pos = 0;
    if (li == 0 && act) pos = (int)atomicAdd(&cursor[dst], 1u);
    pos = __shfl(pos, lane & 32);            // broadcast within half-wave

    f32x4 p = wT[0] * r0.x;
    p += wT[1] * r0.y;
    p += wT[2] * r0.z;
    p += wT[3] * r0.w;
    p += wT[4] * r1.x;
    p += wT[5] * r1.y;
    p += wT[6] * r1.z;
    p += wT[7] * r1.w;
    p *= m4;

    if (act && pos < CAP) {
      unsigned u0 = (unsigned)f2bf(p[0]) | ((unsigned)f2bf(p[1]) << 16);
      unsigned u1 = (unsigned)f2bf(p[2]) | ((unsigned)f2bf(p[3]) << 16);
      // row = 256B; half-wave writes it contiguously (uint2 per lane)
      char* rowp = (char*)payload + ((size_t)dst * CAP + pos) * 256 + li * 8;
      *reinterpret_cast<uint2*>(rowp) = (uint2){u0, u1};
    }
  }
}

// ---------------------------------------------------------------------------
// K2 (new path, phase B): per-atom contiguous reduce of the payload bin.
// Wave per atom; lane owns channels (2l,2l+1) = one uint per 256B row;
// rows are contiguous -> streaming, mostly L2/L3-resident.
// ---------------------------------------------------------------------------
__global__ __launch_bounds__(256) void reduce_kernel(
    const unsigned short* __restrict__ payload,
    const unsigned* __restrict__ cnts,
    unsigned short* __restrict__ node_bf, int num_atoms)
{
  const int lane = threadIdx.x & 63;
  const int wid = blockIdx.x * (blockDim.x >> 6) + (threadIdx.x >> 6);
  if (wid >= num_atoms) return;

  int cnt = (int)cnts[wid];
  if (cnt > CAP) cnt = CAP;
  const unsigned* base =
      reinterpret_cast<const unsigned*>(payload + (size_t)wid * CAP * 128) + lane;

  float a0 = 0.f, a1 = 0.f;
  int r = 0;
  for (; r + 8 <= cnt; r += 8) {
    unsigned u[8];
#pragma unroll
    for (int k = 0; k < 8; ++k) u[k] = base[(r + k) * 64];
#pragma unroll
    for (int k = 0; k < 8; ++k) {
      a0 += __builtin_bit_cast(float, u[k] << 16);
      a1 += __builtin_bit_cast(float, u[k] & 0xffff0000u);
    }
  }
  for (; r < cnt; ++r) {
    unsigned u = base[r * 64];
    a0 += __builtin_bit_cast(float, u << 16);
    a1 += __builtin_bit_cast(float, u & 0xffff0000u);
  }

  unsigned pack = (unsigned)f2bf(a0) | ((unsigned)f2bf(a1) << 16);
  *(reinterpret_cast<unsigned*>(node_bf + (size_t)wid * EMBED) + lane) = pack;
}

// ---------------------------------------------------------------------------
// Fallback path (R6): bucket + random-read gather. Used only if ws too small
// for the payload buffer.
// ---------------------------------------------------------------------------
__global__ __launch_bounds__(256) void bucket_kernel(
    const int* __restrict__ nbr, unsigned* __restrict__ cursor,
    int* __restrict__ sorted, int n_edges)
{
  int i = blockIdx.x * blockDim.x + threadIdx.x;
  const int stride = gridDim.x * blockDim.x;
  const int2* nb = reinterpret_cast<const int2*>(nbr);
  for (; i < n_edges; i += stride) {
    const int dst = nb[i].x;
    unsigned pos = atomicAdd(&cursor[dst], 1u);
    if (pos < CAP) sorted[(size_t)dst * CAP + pos] = i;
  }
}

__global__ __launch_bounds__(256) void gather_kernel(
    const float* __restrict__ m_ji, const float* __restrict__ e_rbf,
    const int* __restrict__ sorted, const unsigned* __restrict__ cnts,
    const float* __restrict__ W_edge, unsigned short* __restrict__ node_bf,
    int num_atoms)
{
  const int lane = threadIdx.x & 63;
  const int li = lane & 31;
  const int half = lane >> 5;
  const int wid = blockIdx.x * (blockDim.x >> 6) + (threadIdx.x >> 6);
  if (wid >= num_atoms) return;

  f32x4 wT[NRBF];
#pragma unroll
  for (int k = 0; k < NRBF; ++k) {
#pragma unroll
    for (int q = 0; q < 4; ++q) wT[k][q] = W_edge[(li * 4 + q) * NRBF + k];
  }

  int cnt = (int)cnts[wid];
  if (cnt > CAP) cnt = CAP;
  const int* sb = sorted + (size_t)wid * CAP;
  const char* mbase = (const char*)m_ji;
  const char* rbase = (const char*)e_rbf;
  const unsigned moff_lane = (unsigned)(li * 16);

  f32x4 acc = {0.f, 0.f, 0.f, 0.f};
  for (int base = 0; base < cnt; base += 64) {
    const int rem = min(64, cnt - base);
    const int myeid = (base + lane < cnt) ? sb[base + lane] : sb[base];
#pragma unroll 4
    for (int j = 0; j < rem; j += 2) {
      const int idx = j + half;
      const float vm = (idx < rem) ? 1.0f : 0.0f;
      const int eid = __shfl(myeid, idx & 63);
      const unsigned mo = ((unsigned)eid << 9) + moff_lane;
      const unsigned ro = (unsigned)eid << 5;
      const f32x4 m4 = *reinterpret_cast<const f32x4*>(mbase + mo);
      const f32x4 r0 = *reinterpret_cast<const f32x4*>(rbase + ro);
      const f32x4 r1 = *reinterpret_cast<const f32x4*>(rbase + ro + 16);
      f32x4 p = wT[0] * r0.x;
      p += wT[1] * r0.y;
      p += wT[2] * r0.z;
      p += wT[3] * r0.w;
      p += wT[4] * r1.x;
      p += wT[5] * r1.y;
      p += wT[6] * r1.z;
      p += wT[7] * r1.w;
      p *= vm;
      acc += p * m4;
    }
  }
  acc[0] += __shfl_xor(acc[0], 32);
  acc[1] += __shfl_xor(acc[1], 32);
  acc[2] += __shfl_xor(acc[2], 32);
  acc[3] += __shfl_xor(acc[3], 32);
  if (half == 0) {
    unsigned u0 = (unsigned)f2bf(acc[0]) | ((unsigned)f2bf(acc[1]) << 16);
    unsigned u1 = (unsigned)f2bf(acc[2]) | ((unsigned)f2bf(acc[3]) << 16);
    uint2 v = {u0, u1};
    *reinterpret_cast<uint2*>(node_bf + (size_t)wid * EMBED + li * 4) = v;
  }
}

// ---------------------------------------------------------------------------
// K3: fused 4-layer MLP on MFMA (bf16 in, f32 accumulate). Unchanged (~5us).
// ---------------------------------------------------------------------------
__global__ __launch_bounds__(256) void mlp_mfma_kernel(
    const unsigned short* __restrict__ node_bf,
    const unsigned short* __restrict__ Wbf,
    const float* __restrict__ bws,
    float* __restrict__ out, int num_atoms)
{
  __shared__ unsigned short x_lds[64 * 128];   // 16 KB
  char* xb = (char*)x_lds;
  const int lane = threadIdx.x & 63;
  const int wave = threadIdx.x >> 6;
  const int rbase = blockIdx.x * 64;

#pragma unroll
  for (int it = 0; it < 4; ++it) {
    int i = it * 64 + lane;
    int r = i >> 4;
    int s = i & 15;
    int row = wave * 16 + r;
    int grow = rbase + row;
    uint4 v = {0u, 0u, 0u, 0u};
    if (grow < num_atoms)
      v = *reinterpret_cast<const uint4*>(node_bf + (size_t)grow * 128 + s * 8);
    *reinterpret_cast<uint4*>(xb + row * 256 + ((s ^ (row & 7)) * 16)) = v;
  }

  const int arow = wave * 16 + (lane & 15);
  const int kb = lane >> 4;
  const int colbase = lane & 15;

  f32x4 acc[8];
#pragma unroll
  for (int layer = 0; layer < 4; ++layer) {
    const unsigned short* W = Wbf + layer * 16384;
#pragma unroll
    for (int t = 0; t < 8; ++t) {
      if (layer < 3) {
        float bv = bws[layer * 128 + t * 16 + colbase];
        acc[t] = (f32x4){bv, bv, bv, bv};
      } else {
        acc[t] = (f32x4){0.f, 0.f, 0.f, 0.f};
      }
    }
#pragma unroll
    for (int ks = 0; ks < 4; ++ks) {
      bf16x8 a = *reinterpret_cast<const bf16x8*>(
          xb + arow * 256 + (((ks * 4 + kb) ^ (arow & 7)) * 16));
#pragma unroll
      for (int t = 0; t < 8; ++t) {
        int col = t * 16 + colbase;
        bf16x8 b = *reinterpret_cast<const bf16x8*>(W + col * 128 + ks * 32 + kb * 8);
        acc[t] = __builtin_amdgcn_mfma_f32_16x16x32_bf16(a, b, acc[t], 0, 0, 0);
      }
    }
    if (layer < 3) {
#pragma unroll
      for (int t = 0; t < 8; ++t) {
        int col = t * 16 + colbase;
        int s = col >> 3;
        int cw = (col & 7) * 2;
#pragma unroll
        for (int j = 0; j < 4; ++j) {
          int row = wave * 16 + (lane >> 4) * 4 + j;
          unsigned short h = f2bf(silu_f(acc[t][j]));
          *reinterpret_cast<unsigned short*>(
              xb + row * 256 + ((s ^ (row & 7)) * 16) + cw) = h;
        }
      }
    } else {
#pragma unroll
      for (int t = 0; t < 8; ++t) {
        int col = t * 16 + colbase;
#pragma unroll
        for (int j = 0; j < 4; ++j) {
          int row = wave * 16 + (lane >> 4) * 4 + j;
          int grow = rbase + row;
          if (grow < num_atoms) out[(size_t)grow * 128 + col] = acc[t][j];
        }
      }
    }
  }
}

extern "C" void kernel_launch(void* const* d_in, const int* in_sizes, int n_in,
                              void* d_out, int out_size, void* d_ws, size_t ws_size,
                              hipStream_t stream) {
  const float* m_ji   = (const float*)d_in[0];
  const float* e_rbf  = (const float*)d_in[1];
  const int*   nbr    = (const int*)d_in[2];
  const float* W_edge = (const float*)d_in[4];
  const float* W1 = (const float*)d_in[5];
  const float* b1 = (const float*)d_in[6];
  const float* W2 = (const float*)d_in[7];
  const float* b2 = (const float*)d_in[8];
  const float* W3 = (const float*)d_in[9];
  const float* b3 = (const float*)d_in[10];
  const float* Wf = (const float*)d_in[11];
  float* out = (float*)d_out;

  const int n_edges   = in_sizes[0] / EMBED;
  const int num_atoms = out_size / EMBED;

  auto align256 = [](size_t x) { return (x + 255) & ~(size_t)255; };
  char* p = (char*)d_ws;
  unsigned short* node_bf = (unsigned short*)p;
  p += align256((size_t)num_atoms * EMBED * sizeof(unsigned short));
  unsigned* cursor    = (unsigned*)p;  p += align256((size_t)num_atoms * 4);
  unsigned short* Wbf = (unsigned short*)p; p += align256((size_t)4 * 128 * 128 * 2);
  float* bws          = (float*)p;     p += align256((size_t)3 * 128 * 4);
  char* tail = p;  // payload (new path) or sorted (fallback) lives here
  const size_t payload_bytes = (size_t)num_atoms * CAP * 256;
  const size_t need_new = (size_t)(tail - (char*)d_ws) + payload_bytes;

  const int prep_blocks = (num_atoms > 16384 ? (num_atoms + 255) / 256 : 64);
  prep_kernel<<<prep_blocks, 256, 0, stream>>>(W1, W2, W3, Wf, b1, b2, b3,
                                               Wbf, bws, cursor, num_atoms);

  if (ws_size >= need_new) {
    unsigned short* payload = (unsigned short*)tail;
    edge_stream_kernel<<<2048, 256, 0, stream>>>(m_ji, e_rbf, nbr, W_edge,
                                                 cursor, payload, n_edges);
    const int rblocks = (num_atoms + 3) / 4;
    reduce_kernel<<<rblocks, 256, 0, stream>>>(payload, cursor, node_bf,
                                               num_atoms);
  } else {
    int* sorted = (int*)tail;
    bucket_kernel<<<1024, 256, 0, stream>>>(nbr, cursor, sorted, n_edges);
    const int gblocks = (num_atoms + 3) / 4;
    gather_kernel<<<gblocks, 256, 0, stream>>>(m_ji, e_rbf, sorted, cursor,
                                               W_edge, node_bf, num_atoms);
  }

  const int mlp_blocks = (num_atoms + 63) / 64;
  mlp_mfma_kernel<<<mlp_blocks, 256, 0, stream>>>(node_bf, Wbf, bws, out, num_atoms);
}

// Round 8
// 154.429 us; speedup vs baseline: 1.1359x; 1.1359x over previous
//
#include <hip/hip_runtime.h>

#define EMBED 128
#define NRBF 8
#define CAP 160   // per-atom edge capacity; mean 64, sigma 8 (binomial) -> 12 sigma

typedef __attribute__((ext_vector_type(8))) short bf16x8;
typedef __attribute__((ext_vector_type(4))) float f32x4;

static __device__ __forceinline__ unsigned short f2bf(float f) {
  unsigned u = __builtin_bit_cast(unsigned, f);
  u = (u + 0x7fffu + ((u >> 16) & 1u)) >> 16;  // round-to-nearest-even
  return (unsigned short)u;
}

static __device__ __forceinline__ float silu_f(float x) {
  return x / (1.0f + __expf(-x));
}

// ---------------------------------------------------------------------------
// K0: prep — zero cursor, convert 4 weights to bf16, pack biases.
// ---------------------------------------------------------------------------
__global__ __launch_bounds__(256) void prep_kernel(
    const float* __restrict__ W1, const float* __restrict__ W2,
    const float* __restrict__ W3, const float* __restrict__ Wf,
    const float* __restrict__ b1, const float* __restrict__ b2,
    const float* __restrict__ b3,
    unsigned short* __restrict__ Wbf, float* __restrict__ bws,
    unsigned* __restrict__ cursor, int num_atoms)
{
  int i = blockIdx.x * 256 + threadIdx.x;
  if (i < 16384) {
    Wbf[i]         = f2bf(W1[i]);
    Wbf[16384 + i] = f2bf(W2[i]);
    Wbf[32768 + i] = f2bf(W3[i]);
    Wbf[49152 + i] = f2bf(Wf[i]);
  }
  if (i < 128) {
    bws[i] = b1[i]; bws[128 + i] = b2[i]; bws[256 + i] = b3[i];
  }
  if (i < num_atoms) cursor[i] = 0u;
}

// ---------------------------------------------------------------------------
// K1: bucket edge ids by destination atom into fixed-capacity bins.
// cursor[dst] ends up holding the bin count.
// ---------------------------------------------------------------------------
__global__ __launch_bounds__(256) void bucket_kernel(
    const int* __restrict__ nbr, unsigned* __restrict__ cursor,
    int* __restrict__ sorted, int n_edges)
{
  int i = blockIdx.x * blockDim.x + threadIdx.x;
  const int stride = gridDim.x * blockDim.x;
  const int2* nb = reinterpret_cast<const int2*>(nbr);
  for (; i < n_edges; i += stride) {
    const int dst = nb[i].x;
    unsigned pos = atomicAdd(&cursor[dst], 1u);
    if (pos < CAP) sorted[(size_t)dst * CAP + pos] = i;
  }
}

// ---------------------------------------------------------------------------
// K2: gather-reduce v3 (R6, measured best). One wave per atom, half-wave per
// edge (2 edges per wave-instruction, f32x4/lane = 1KB per m-load);
// transposed W_edge in registers -> v_pk_fma_f32; 32-bit byte-offset
// addressing; tail mask folded into one f32x4 mul.
// Measured: ~120us, random-request-path-bound (~2.9 TB/s effective; see
// session notes R5-R7: instruction cut = null, dataflow inversion = worse,
// Little's law rules out latency-bound).
// ---------------------------------------------------------------------------
__global__ __launch_bounds__(256) void gather_kernel(
    const float* __restrict__ m_ji, const float* __restrict__ e_rbf,
    const int* __restrict__ sorted, const unsigned* __restrict__ cnts,
    const float* __restrict__ W_edge, unsigned short* __restrict__ node_bf,
    int num_atoms)
{
  const int lane = threadIdx.x & 63;
  const int li = lane & 31;
  const int half = lane >> 5;
  const int wid = blockIdx.x * (blockDim.x >> 6) + (threadIdx.x >> 6);
  if (wid >= num_atoms) return;

  // transposed weights: wT[k][q] = W_edge[(li*4+q)*8 + k]
  f32x4 wT[NRBF];
#pragma unroll
  for (int k = 0; k < NRBF; ++k) {
#pragma unroll
    for (int q = 0; q < 4; ++q) wT[k][q] = W_edge[(li * 4 + q) * NRBF + k];
  }

  int cnt = (int)cnts[wid];
  if (cnt > CAP) cnt = CAP;
  const int* sb = sorted + (size_t)wid * CAP;
  const char* mbase = (const char*)m_ji;
  const char* rbase = (const char*)e_rbf;
  const unsigned moff_lane = (unsigned)(li * 16);

  f32x4 acc = {0.f, 0.f, 0.f, 0.f};

  for (int base = 0; base < cnt; base += 64) {
    const int rem = min(64, cnt - base);
    const int myeid = (base + lane < cnt) ? sb[base + lane] : sb[base];
#pragma unroll 4
    for (int j = 0; j < rem; j += 2) {
      const int idx = j + half;                   // edge slot for this half-wave
      const float vm = (idx < rem) ? 1.0f : 0.0f; // mask odd tail
      const int eid = __shfl(myeid, idx & 63);
      const unsigned mo = ((unsigned)eid << 9) + moff_lane;
      const unsigned ro = (unsigned)eid << 5;
      const f32x4 m4 = *reinterpret_cast<const f32x4*>(mbase + mo);
      const f32x4 r0 = *reinterpret_cast<const f32x4*>(rbase + ro);
      const f32x4 r1 = *reinterpret_cast<const f32x4*>(rbase + ro + 16);

      f32x4 p = wT[0] * r0.x;
      p += wT[1] * r0.y;
      p += wT[2] * r0.z;
      p += wT[3] * r0.w;
      p += wT[4] * r1.x;
      p += wT[5] * r1.y;
      p += wT[6] * r1.z;
      p += wT[7] * r1.w;
      p *= vm;
      acc += p * m4;
    }
  }

  // combine the two half-wave partial sums (same channels, different edges)
  acc[0] += __shfl_xor(acc[0], 32);
  acc[1] += __shfl_xor(acc[1], 32);
  acc[2] += __shfl_xor(acc[2], 32);
  acc[3] += __shfl_xor(acc[3], 32);

  if (half == 0) {
    unsigned u0 = (unsigned)f2bf(acc[0]) | ((unsigned)f2bf(acc[1]) << 16);
    unsigned u1 = (unsigned)f2bf(acc[2]) | ((unsigned)f2bf(acc[3]) << 16);
    uint2 v = {u0, u1};
    *reinterpret_cast<uint2*>(node_bf + (size_t)wid * EMBED + li * 4) = v;
  }
}

// ---------------------------------------------------------------------------
// K3: fused 4-layer MLP on MFMA (bf16 in, f32 accumulate), ~5us.
// 64 rows/block, 4 waves, wave-private rows -> no barriers; XOR-swizzled
// LDS A-tile; B straight from L2-hot bf16 weights.
// ---------------------------------------------------------------------------
__global__ __launch_bounds__(256) void mlp_mfma_kernel(
    const unsigned short* __restrict__ node_bf,
    const unsigned short* __restrict__ Wbf,
    const float* __restrict__ bws,
    float* __restrict__ out, int num_atoms)
{
  __shared__ unsigned short x_lds[64 * 128];   // 16 KB
  char* xb = (char*)x_lds;
  const int lane = threadIdx.x & 63;
  const int wave = threadIdx.x >> 6;
  const int rbase = blockIdx.x * 64;

#pragma unroll
  for (int it = 0; it < 4; ++it) {
    int i = it * 64 + lane;
    int r = i >> 4;
    int s = i & 15;
    int row = wave * 16 + r;
    int grow = rbase + row;
    uint4 v = {0u, 0u, 0u, 0u};
    if (grow < num_atoms)
      v = *reinterpret_cast<const uint4*>(node_bf + (size_t)grow * 128 + s * 8);
    *reinterpret_cast<uint4*>(xb + row * 256 + ((s ^ (row & 7)) * 16)) = v;
  }

  const int arow = wave * 16 + (lane & 15);
  const int kb = lane >> 4;
  const int colbase = lane & 15;

  f32x4 acc[8];
#pragma unroll
  for (int layer = 0; layer < 4; ++layer) {
    const unsigned short* W = Wbf + layer * 16384;
#pragma unroll
    for (int t = 0; t < 8; ++t) {
      if (layer < 3) {
        float bv = bws[layer * 128 + t * 16 + colbase];
        acc[t] = (f32x4){bv, bv, bv, bv};
      } else {
        acc[t] = (f32x4){0.f, 0.f, 0.f, 0.f};
      }
    }
#pragma unroll
    for (int ks = 0; ks < 4; ++ks) {
      bf16x8 a = *reinterpret_cast<const bf16x8*>(
          xb + arow * 256 + (((ks * 4 + kb) ^ (arow & 7)) * 16));
#pragma unroll
      for (int t = 0; t < 8; ++t) {
        int col = t * 16 + colbase;
        bf16x8 b = *reinterpret_cast<const bf16x8*>(W + col * 128 + ks * 32 + kb * 8);
        acc[t] = __builtin_amdgcn_mfma_f32_16x16x32_bf16(a, b, acc[t], 0, 0, 0);
      }
    }
    if (layer < 3) {
#pragma unroll
      for (int t = 0; t < 8; ++t) {
        int col = t * 16 + colbase;
        int s = col >> 3;
        int cw = (col & 7) * 2;
#pragma unroll
        for (int j = 0; j < 4; ++j) {
          int row = wave * 16 + (lane >> 4) * 4 + j;
          unsigned short h = f2bf(silu_f(acc[t][j]));
          *reinterpret_cast<unsigned short*>(
              xb + row * 256 + ((s ^ (row & 7)) * 16) + cw) = h;
        }
      }
    } else {
#pragma unroll
      for (int t = 0; t < 8; ++t) {
        int col = t * 16 + colbase;
#pragma unroll
        for (int j = 0; j < 4; ++j) {
          int row = wave * 16 + (lane >> 4) * 4 + j;
          int grow = rbase + row;
          if (grow < num_atoms) out[(size_t)grow * 128 + col] = acc[t][j];
        }
      }
    }
  }
}

extern "C" void kernel_launch(void* const* d_in, const int* in_sizes, int n_in,
                              void* d_out, int out_size, void* d_ws, size_t ws_size,
                              hipStream_t stream) {
  const float* m_ji   = (const float*)d_in[0];
  const float* e_rbf  = (const float*)d_in[1];
  const int*   nbr    = (const int*)d_in[2];
  const float* W_edge = (const float*)d_in[4];
  const float* W1 = (const float*)d_in[5];
  const float* b1 = (const float*)d_in[6];
  const float* W2 = (const float*)d_in[7];
  const float* b2 = (const float*)d_in[8];
  const float* W3 = (const float*)d_in[9];
  const float* b3 = (const float*)d_in[10];
  const float* Wf = (const float*)d_in[11];
  float* out = (float*)d_out;

  const int n_edges   = in_sizes[0] / EMBED;
  const int num_atoms = out_size / EMBED;

  auto align256 = [](size_t x) { return (x + 255) & ~(size_t)255; };
  char* p = (char*)d_ws;
  unsigned short* node_bf = (unsigned short*)p;
  p += align256((size_t)num_atoms * EMBED * sizeof(unsigned short));
  unsigned* cursor    = (unsigned*)p;  p += align256((size_t)num_atoms * 4);
  int* sorted         = (int*)p;       p += align256((size_t)num_atoms * CAP * 4);
  unsigned short* Wbf = (unsigned short*)p; p += align256((size_t)4 * 128 * 128 * 2);
  float* bws          = (float*)p;     p += align256((size_t)3 * 128 * 4);

  // prep (weights->bf16, biases, zero cursor)
  const int prep_blocks = (num_atoms > 16384 ? (num_atoms + 255) / 256 : 64);
  prep_kernel<<<prep_blocks, 256, 0, stream>>>(W1, W2, W3, Wf, b1, b2, b3,
                                               Wbf, bws, cursor, num_atoms);

  // bucket edge ids by destination (fixed-capacity bins; cursor -> counts)
  bucket_kernel<<<1024, 256, 0, stream>>>(nbr, cursor, sorted, n_edges);

  // gather-reduce into bf16 node feats
  const int gblocks = (num_atoms + 3) / 4;
  gather_kernel<<<gblocks, 256, 0, stream>>>(m_ji, e_rbf, sorted, cursor,
                                             W_edge, node_bf, num_atoms);

  // fused MFMA MLP
  const int mlp_blocks = (num_atoms + 63) / 64;
  mlp_mfma_kernel<<<mlp_blocks, 256, 0, stream>>>(node_bf, Wbf, bws, out, num_atoms);
}